// Round 4
// baseline (38.709 us; speedup 1.0000x reference)
//
#include <hip/hip_runtime.h>
#include <hip/hip_bf16.h>

#define HW 16384
#define NB 4

typedef __attribute__((ext_vector_type(8))) short bf16x8;
typedef __attribute__((ext_vector_type(4))) float f32x4;

__device__ __forceinline__ float blo(unsigned u) { return __uint_as_float(u << 16); }
__device__ __forceinline__ float bhi(unsigned u) { return __uint_as_float(u & 0xffff0000u); }

// ws byte layout:
// [0,16384)          Wbf16 [2][64 d][64 c] ushort  (0=keys, 1=queries)
// [16384,16896)      combined bias f32 [128]
// [32768,+8.4MB)     keys    bf16 [4][16384][64]
// [.. ,+8.4MB)       queries bf16 [4][16384][64]

// ---------------- Kernel A: fold linear layers (LDS-free) ----------------
// W row is wave-uniform -> s_loads; conv_w column is lane-coalesced.
__global__ __launch_bounds__(256) void combine_weights(
    const float* __restrict__ conv_w, const float* __restrict__ conv_b,
    const float* __restrict__ key_w, const float* __restrict__ key_b,
    const float* __restrict__ query_w, const float* __restrict__ query_b,
    ushort* __restrict__ Wb, float* __restrict__ bout) {
    int t = threadIdx.x, bx = blockIdx.x;
    int sel = bx >> 4, d0 = (bx & 15) * 4;
    const float* Wm = sel ? query_w : key_w;
    int dd = t >> 6, c = t & 63;
    const float* wrow = Wm + (d0 + dd) * 64;   // wave-uniform
    float acc = 0.f;
    #pragma unroll
    for (int k = 0; k < 64; ++k) acc = fmaf(wrow[k], conv_w[k * 64 + c], acc);
    __hip_bfloat16 h = __float2bfloat16(acc);
    Wb[(sel * 64 + d0 + dd) * 64 + c] = *(ushort*)&h;
    if (t < 4) {
        const float* wr2 = Wm + (d0 + t) * 64;
        float bacc = 0.f;
        #pragma unroll
        for (int k = 0; k < 64; ++k) bacc = fmaf(wr2[k], conv_b[k], bacc);
        bacc += (sel ? query_b : key_b)[d0 + t];
        bout[sel * 64 + d0 + t] = bacc;
    }
}

// ---------------- Kernel B: MFMA GEMM, 64-node tiles, high occupancy ----------------
__global__ __launch_bounds__(256) void gemm_kq(
    const float* __restrict__ x, const ushort* __restrict__ W,
    const float* __restrict__ bias, ushort* __restrict__ keys,
    ushort* __restrict__ queries) {
    __shared__ ushort xs[64 * 64];    // [n][c] bf16, 16B-chunk XOR swizzle
    __shared__ ushort epi[64 * 64];   // [n][64 d] bf16 per phase
    __shared__ float bs[128];
    int t = threadIdx.x;
    int b = blockIdx.x >> 8;
    int n0 = (blockIdx.x & 255) << 6;

    if (t < 128) bs[t] = bias[t];
    {   // stage x: thread -> node t&63, channel quarter t>>6 (16 ch), cvt bf16
        int r = t & 63, q0 = t >> 6;
        const float* xp = x + ((size_t)(b * 64 + q0 * 16)) * HW + n0 + r;
        unsigned u[8];
        #pragma unroll
        for (int cc = 0; cc < 8; ++cc) {
            float lo = xp[(size_t)(2 * cc) * HW];
            float hi = xp[(size_t)(2 * cc + 1) * HW];
            __hip_bfloat162 h2 = __float22bfloat162_rn(make_float2(lo, hi));
            u[cc] = *(unsigned*)&h2;
        }
        #pragma unroll
        for (int q = 0; q < 2; ++q) {
            int qq = q0 * 2 + q;
            *(uint4*)((char*)xs + r * 128 + ((qq ^ (r & 7)) << 4)) =
                make_uint4(u[4 * q], u[4 * q + 1], u[4 * q + 2], u[4 * q + 3]);
        }
    }
    __syncthreads();

    int l = t & 63, w = t >> 6;
    int ncol = l & 15, kg = l >> 4;

    bf16x8 Bf[2];
    int brow = w * 16 + ncol;
    #pragma unroll
    for (int half = 0; half < 2; ++half)
        Bf[half] = *(bf16x8*)((char*)xs + brow * 128 + (((half * 4 + kg) ^ (brow & 7)) << 4));

    f32x4 acc[8];
    #pragma unroll
    for (int dt = 0; dt < 8; ++dt) acc[dt] = (f32x4){0.f, 0.f, 0.f, 0.f};

    #pragma unroll
    for (int dt = 0; dt < 8; ++dt) {
        const bf16x8* arow = (const bf16x8*)(W + (dt * 16 + ncol) * 64 + kg * 8);
        acc[dt] = __builtin_amdgcn_mfma_f32_16x16x32_bf16(arow[0], Bf[0], acc[dt], 0, 0, 0);
        acc[dt] = __builtin_amdgcn_mfma_f32_16x16x32_bf16(arow[4], Bf[1], acc[dt], 0, 0, 0);
    }

    #pragma unroll
    for (int p = 0; p < 2; ++p) {
        #pragma unroll
        for (int dt = 0; dt < 4; ++dt) {
            int dbase = dt * 16 + kg * 4;
            float4 bb = *(float4*)&bs[p * 64 + dbase];
            int n = w * 16 + ncol;
            f32x4 a = acc[p * 4 + dt];
            __hip_bfloat162 lo2 = __float22bfloat162_rn(make_float2(a[0] + bb.x, a[1] + bb.y));
            __hip_bfloat162 hi2 = __float22bfloat162_rn(make_float2(a[2] + bb.z, a[3] + bb.w));
            *(uint2*)((char*)epi + n * 128 + (((dbase >> 3) ^ (n & 7)) << 4) + ((dbase & 4) << 1)) =
                make_uint2(*(unsigned*)&lo2, *(unsigned*)&hi2);
        }
        __syncthreads();
        ushort* dst = p ? queries : keys;
        #pragma unroll
        for (int i = 0; i < 2; ++i) {
            int idx = i * 256 + t;
            int row = idx >> 3, ch = idx & 7;
            uint4 v = *(uint4*)((char*)epi + row * 128 + ((ch ^ (row & 7)) << 4));
            *(uint4*)(dst + (((size_t)(b * HW + n0 + row)) << 6) + ch * 8) = v;
        }
        __syncthreads();
    }
}

// ---------------- Kernel C: gather + dot, literal window offsets ----------------
#define DOT(s_, idxn_) do {                                                   \
    const uint4* kp = (const uint4*)(kb_ + ((size_t)(idxn_) << 6));           \
    uint4 ka = kp[0], kc = kp[1];                                             \
    float a = 0.f;                                                            \
    a = fmaf(blo(ka.x), qf[0], a);  a = fmaf(bhi(ka.x), qf[1], a);            \
    a = fmaf(blo(ka.y), qf[2], a);  a = fmaf(bhi(ka.y), qf[3], a);            \
    a = fmaf(blo(ka.z), qf[4], a);  a = fmaf(bhi(ka.z), qf[5], a);            \
    a = fmaf(blo(ka.w), qf[6], a);  a = fmaf(bhi(ka.w), qf[7], a);            \
    a = fmaf(blo(kc.x), qf[8], a);  a = fmaf(bhi(kc.x), qf[9], a);            \
    a = fmaf(blo(kc.y), qf[10], a); a = fmaf(bhi(kc.y), qf[11], a);           \
    a = fmaf(blo(kc.z), qf[12], a); a = fmaf(bhi(kc.z), qf[13], a);           \
    a = fmaf(blo(kc.w), qf[14], a); a = fmaf(bhi(kc.w), qf[15], a);           \
    a += __shfl_xor(a, 1);                                                    \
    a += __shfl_xor(a, 2);                                                    \
    if (j == 0) res[n_loc * 26 + (s_)] = a * 0.125f;                          \
} while (0)

#define SAMP(s_, dy_, dx_) do {                                               \
    int ry = y + (dy_);                                                       \
    if ((dy_) < 0) ry = (ry < 0) ? -ry : ry;                                  \
    if ((dy_) > 0) ry = (ry > 127) ? 254 - ry : ry;                           \
    int rx = xq + (dx_);                                                      \
    if ((dx_) < 0) rx = (rx < 0) ? -rx : rx;                                  \
    if ((dx_) > 0) rx = (rx > 127) ? 254 - rx : rx;                           \
    DOT(s_, (ry << 7) + rx);                                                  \
} while (0)

__global__ __launch_bounds__(256) void affinity(
    const ushort* __restrict__ keys, const ushort* __restrict__ queries,
    const int* __restrict__ rnd, float* __restrict__ out) {
    __shared__ float res[416];
    int t = threadIdx.x;
    int b = blockIdx.x >> 10;
    int n0 = (blockIdx.x & 1023) << 4;

    int j = t & 3;
    int g = t >> 2;
    int n_loc = g & 15;
    int sb = g >> 4;          // wave-uniform sample phase
    int n = n0 + n_loc;

    const uint4* qp = (const uint4*)(queries + (((size_t)(b * HW + n)) << 6) + j * 16);
    uint4 qa = qp[0], qb = qp[1];
    float qf[16];
    qf[0] = blo(qa.x); qf[1] = bhi(qa.x); qf[2] = blo(qa.y); qf[3] = bhi(qa.y);
    qf[4] = blo(qa.z); qf[5] = bhi(qa.z); qf[6] = blo(qa.w); qf[7] = bhi(qa.w);
    qf[8] = blo(qb.x); qf[9] = bhi(qb.x); qf[10] = blo(qb.y); qf[11] = bhi(qb.y);
    qf[12] = blo(qb.z); qf[13] = bhi(qb.z); qf[14] = blo(qb.w); qf[15] = bhi(qb.w);

    int y = n >> 7, xq = n & 127;
    const ushort* kb_ = keys + (((size_t)b * HW) << 6) + j * 16;

    switch (sb) {
    case 0:
        SAMP(0, -2, -2); SAMP(4, -2, 2);  SAMP(8, -1, 1);  SAMP(12, 0, 0);
        SAMP(16, 1, -1); SAMP(20, 2, -2); SAMP(24, 2, 2);
        break;
    case 1: {
        SAMP(1, -2, -1); SAMP(5, -1, -2); SAMP(9, -1, 2);  SAMP(13, 0, 1);
        SAMP(17, 1, 0);  SAMP(21, 2, -1);
        int rix = rnd[b * HW + n];
        DOT(25, rix);
        break;
    }
    case 2:
        SAMP(2, -2, 0);  SAMP(6, -1, -1); SAMP(10, 0, -2); SAMP(14, 0, 2);
        SAMP(18, 1, 1);  SAMP(22, 2, 0);
        break;
    default:
        SAMP(3, -2, 1);  SAMP(7, -1, 0);  SAMP(11, 0, -1); SAMP(15, 1, -2);
        SAMP(19, 1, 2);  SAMP(23, 2, 1);
        break;
    }
    __syncthreads();
    size_t ob = ((size_t)(b * HW + n0)) * 26;
    out[ob + t] = res[t];
    if (t < 160) out[ob + 256 + t] = res[256 + t];
}

extern "C" void kernel_launch(void* const* d_in, const int* in_sizes, int n_in,
                              void* d_out, int out_size, void* d_ws, size_t ws_size,
                              hipStream_t stream) {
    const float* x       = (const float*)d_in[0];
    const float* conv_w  = (const float*)d_in[1];
    const float* conv_b  = (const float*)d_in[2];
    const float* key_w   = (const float*)d_in[3];
    const float* key_b   = (const float*)d_in[4];
    const float* query_w = (const float*)d_in[5];
    const float* query_b = (const float*)d_in[6];
    const int*   rnd     = (const int*)d_in[7];
    float* out = (float*)d_out;

    ushort* Wb    = (ushort*)d_ws;
    float*  biasp = (float*)((char*)d_ws + 16384);
    ushort* keys  = (ushort*)((char*)d_ws + 32768);
    ushort* quer  = keys + (size_t)NB * HW * 64;

    combine_weights<<<32, 256, 0, stream>>>(conv_w, conv_b, key_w, key_b,
                                            query_w, query_b, Wb, biasp);
    gemm_kq<<<NB * (HW / 64), 256, 0, stream>>>(x, Wb, biasp, keys, quer);
    affinity<<<NB * (HW / 16), 256, 0, stream>>>(keys, quer, rnd, out);
}